// Round 2
// baseline (599.827 us; speedup 1.0000x reference)
//
#include <hip/hip_runtime.h>

typedef short bf16x8 __attribute__((ext_vector_type(8)));
typedef float f32x4  __attribute__((ext_vector_type(4)));

__device__ __forceinline__ unsigned short f2bf(float f) {
  unsigned int u = __float_as_uint(f);
  u += 0x7fffu + ((u >> 16) & 1u);   // round-to-nearest-even
  return (unsigned short)(u >> 16);
}
__device__ __forceinline__ short f2bfs(float f) { return (short)f2bf(f); }
__device__ __forceinline__ f32x4 fzero() { f32x4 z = {0.f,0.f,0.f,0.f}; return z; }

#define WQKV_FRAGS (6*36*64)          /* 13824 fragment-rows */
#define WP_FRAGS   (6*12*64)          /* 4608  fragment-rows */
#define WQKV_ELEMS (WQKV_FRAGS*8)

// ---------------------------------------------------------------------------
// Prepack: Wqkv fp32 -> bf16 B-frag order (lane l: B[kt*32+(l>>4)*8+j][nt*16+(l&15)]),
// K-columns pre-scaled. Wproj -> Wp^T in A-frag order:
// frag (kt2,ms2), lane l: A[m=e=ms2*16+(l&15)][k=cc=kt2*32+(l>>4)*8+j] = Wp[cc][e].
// ---------------------------------------------------------------------------
__global__ void prepack_weights(const float* __restrict__ wqkv,
                                const float* __restrict__ wproj,
                                unsigned short* __restrict__ ws) {
  int t = blockIdx.x * 256 + threadIdx.x;
  const float scale = 0.20412414523193154f;  // (192/8)^-0.5
  if (t < WQKV_FRAGS) {
    int kt  = t / 2304;
    int rem = t - kt*2304;
    int nt  = rem >> 6;
    int l   = rem & 63;
    int n   = nt*16 + (l & 15);
    int k0  = kt*32 + (l >> 4)*8;
    float s = (n >= 192 && n < 384) ? scale : 1.0f;
    union { unsigned short us[8]; uint4 v; } u;
#pragma unroll
    for (int j = 0; j < 8; ++j) u.us[j] = f2bf(wqkv[(k0 + j)*576 + n] * s);
    *(uint4*)(ws + (size_t)t * 8) = u.v;
  } else if (t < WQKV_FRAGS + WP_FRAGS) {
    int t2   = t - WQKV_FRAGS;
    int kt2g = t2 / 768;
    int rem  = t2 - kt2g*768;
    int ms2  = rem >> 6;
    int l    = rem & 63;
    int e    = ms2*16 + (l & 15);
    int cc0  = kt2g*32 + (l >> 4)*8;
    union { unsigned short us[8]; uint4 v; } u;
#pragma unroll
    for (int j = 0; j < 8; ++j) u.us[j] = f2bf(wproj[(cc0 + j)*192 + e]);
    *(uint4*)(ws + (size_t)WQKV_ELEMS + (size_t)t2 * 8) = u.v;
  }
}

// ---------------------------------------------------------------------------
// Fused per-window kernel. 1 block = 1 window. 512 thr = 8 waves.
// Waves 0-3: attn-row half 0 (cc 0..95); waves 4-7: half 1 (cc 96..191).
// LDS map (107264 B total):
//   [0,25600)      sX   64x200 bf16      -> sAtt rows (post bar3a) -> sEpi
//   [25600,53248)  sKt 192x72 bf16       -> sAtt / sEpi
//   [53248,80896)  sVt 192x72 bf16       -> sAtt tail + sSum/sInv
//   [80896,106496) sQ   64x200 bf16
//   [106496,107264) sBias 192 f32
//   sAtt = base+0, 192x200 bf16 (76800) ; sSum @76800 f32[192][4];
//   sInv @79872 f32[192]; sEpi = base+0, 64x200 f32 (51200)
// ---------------------------------------------------------------------------
__launch_bounds__(512, 2)
__global__ void win_attn_fused(const float* __restrict__ x,
                               const unsigned short* __restrict__ wqkv_sw,
                               const unsigned short* __restrict__ wp_sw,
                               const float* __restrict__ bias,
                               float* __restrict__ out) {
  __shared__ __align__(16) unsigned char smem[107264];
  unsigned short* sX   = (unsigned short*)(smem);
  unsigned short* sKt  = (unsigned short*)(smem + 25600);
  unsigned short* sVt  = (unsigned short*)(smem + 53248);
  unsigned short* sQ   = (unsigned short*)(smem + 80896);
  unsigned short* sAtt = (unsigned short*)(smem);
  float* sSum  = (float*)(smem + 76800);
  float* sInv  = (float*)(smem + 79872);
  float* sEpi  = (float*)(smem);
  float* sBias = (float*)(smem + 106496);

  const int tid  = threadIdx.x;
  const int lane = tid & 63;
  const int wv   = tid >> 6;
  const int l16  = lane & 15;
  const int lq   = lane >> 4;
  const int h    = wv >> 2;        // cc-half
  const int q    = wv & 3;         // sub-index within half (also token-tile nt)

  // ---- P0: stage X -> bf16 LDS; bias -> LDS ----
  if (tid < 192) sBias[tid] = bias[tid];
  {
    const float4* xg = (const float4*)(x + (size_t)blockIdx.x * 12288);
#pragma unroll
    for (int i = 0; i < 6; ++i) {
      int idx = tid + i * 512;
      float4 v = xg[idx];
      int e = idx << 2;
      unsigned short* p = sX + (e / 192) * 200 + (e % 192);
      union { unsigned short us[4]; unsigned long long d; } u;
      u.us[0]=f2bf(v.x); u.us[1]=f2bf(v.y); u.us[2]=f2bf(v.z); u.us[3]=f2bf(v.w);
      *(unsigned long long*)p = u.d;
    }
  }
  __syncthreads();   // bar1

  // ---- G1: QKV = X @ Wqkv (M=64,N=576,K=192); write sQ/sKt/sVt ----
  {
    bf16x8 af[4][6];
#pragma unroll
    for (int ms = 0; ms < 4; ++ms)
#pragma unroll
      for (int kt = 0; kt < 6; ++kt)
        af[ms][kt] = *(const bf16x8*)(sX + (ms*16 + l16)*200 + kt*32 + lq*8);

    for (int nt = wv; nt < 36; nt += 8) {
      f32x4 acc[4] = {fzero(), fzero(), fzero(), fzero()};
      const bf16x8* bp = (const bf16x8*)wqkv_sw + nt*64 + lane;
#pragma unroll
      for (int kt = 0; kt < 6; ++kt) {
        bf16x8 b = bp[kt * 2304];
#pragma unroll
        for (int ms = 0; ms < 4; ++ms)
          acc[ms] = __builtin_amdgcn_mfma_f32_16x16x32_bf16(af[ms][kt], b, acc[ms], 0, 0, 0);
      }
      int c = nt*16 + l16;
#pragma unroll
      for (int ms = 0; ms < 4; ++ms) {
        int rb = ms*16 + lq*4;
        if (c < 192) {
#pragma unroll
          for (int r = 0; r < 4; ++r) sQ[(rb + r)*200 + c] = f2bf(acc[ms][r]);
        } else if (c < 384) {
#pragma unroll
          for (int r = 0; r < 4; ++r) sKt[(c - 192)*72 + rb + r] = f2bf(acc[ms][r]);
        } else {
#pragma unroll
          for (int r = 0; r < 4; ++r) sVt[(c - 384)*72 + rb + r] = f2bf(acc[ms][r]);
        }
      }
    }
  }
  __syncthreads();   // bar2

  // ---- G2: logits for half h: M=96 cc, N=192 d (3 dt-tiles/wave), K=64 n ----
  f32x4 acc2[6][3];
  float p24[24];
  {
    bf16x8 ak[6][2];
#pragma unroll
    for (int ms = 0; ms < 6; ++ms)
#pragma unroll
      for (int kt = 0; kt < 2; ++kt)
        ak[ms][kt] = *(const bf16x8*)(sKt + (h*96 + ms*16 + l16)*72 + kt*32 + lq*8);
#pragma unroll
    for (int ms = 0; ms < 6; ++ms)
#pragma unroll
      for (int dc = 0; dc < 3; ++dc) acc2[ms][dc] = fzero();
#pragma unroll
    for (int dc = 0; dc < 3; ++dc) {
      int dt = q + dc*4;
      bf16x8 bv[2];
#pragma unroll
      for (int kt = 0; kt < 2; ++kt)
        bv[kt] = *(const bf16x8*)(sVt + (dt*16 + l16)*72 + kt*32 + lq*8);
#pragma unroll
      for (int kt = 0; kt < 2; ++kt)
#pragma unroll
        for (int ms = 0; ms < 6; ++ms)
          acc2[ms][dc] = __builtin_amdgcn_mfma_f32_16x16x32_bf16(ak[ms][kt], bv[kt], acc2[ms][dc], 0, 0, 0);
    }
    // exp (no max-sub: logits are O(1)) + per-wave row partial sums
#pragma unroll
    for (int ms = 0; ms < 6; ++ms)
#pragma unroll
      for (int dc = 0; dc < 3; ++dc)
#pragma unroll
        for (int r = 0; r < 4; ++r) acc2[ms][dc][r] = __expf(acc2[ms][dc][r]);
#pragma unroll
    for (int ms = 0; ms < 6; ++ms)
#pragma unroll
      for (int r = 0; r < 4; ++r) {
        float s = acc2[ms][0][r] + acc2[ms][1][r] + acc2[ms][2][r];
        s += __shfl_xor(s, 1); s += __shfl_xor(s, 2);
        s += __shfl_xor(s, 4); s += __shfl_xor(s, 8);
        p24[ms*4 + r] = s;     // sum over this wave's 48 d's, rows ms*16+lq*4+r
      }
  }
  __syncthreads();   // bar3a (alias safety: sAtt overwrites sX/sKt/sVt)

  {
#pragma unroll
    for (int ms = 0; ms < 6; ++ms) {
      int cc = h*96 + ms*16 + lq*4;
#pragma unroll
      for (int dc = 0; dc < 3; ++dc) {
        int d = (q + dc*4)*16 + l16;
#pragma unroll
        for (int r = 0; r < 4; ++r)
          sAtt[(cc + r)*200 + d] = f2bf(acc2[ms][dc][r]);
      }
    }
    if (l16 == 0) {
#pragma unroll
      for (int ms = 0; ms < 6; ++ms)
#pragma unroll
        for (int r = 0; r < 4; ++r)
          sSum[(h*96 + ms*16 + lq*4 + r)*4 + q] = p24[ms*4 + r];
    }
  }
  __syncthreads();   // bar3b (attn + partials ready)

  if (tid < 192) {
    float s = sSum[tid*4] + sSum[tid*4+1] + sSum[tid*4+2] + sSum[tid*4+3];
    sInv[tid] = 1.0f / s;
  }

  // ---- G3': out^T[cc][token] = attn(exp) @ Q^T ; half h, token-tile q ----
  f32x4 acc3[6];
#pragma unroll
  for (int ms = 0; ms < 6; ++ms) acc3[ms] = fzero();
#pragma unroll
  for (int kt = 0; kt < 6; ++kt) {
    bf16x8 bq = *(const bf16x8*)(sQ + (q*16 + l16)*200 + kt*32 + lq*8);
#pragma unroll
    for (int ms = 0; ms < 6; ++ms) {
      bf16x8 a = *(const bf16x8*)(sAtt + (h*96 + ms*16 + l16)*200 + kt*32 + lq*8);
      acc3[ms] = __builtin_amdgcn_mfma_f32_16x16x32_bf16(a, bq, acc3[ms], 0, 0, 0);
    }
  }
  __syncthreads();   // bar4 (sInv ready; all sAtt/sQ reads done -> sEpi reuse safe)

#pragma unroll
  for (int ms = 0; ms < 6; ++ms) {
    f32x4 inv = *(const f32x4*)(sInv + h*96 + ms*16 + lq*4);
#pragma unroll
    for (int r = 0; r < 4; ++r) acc3[ms][r] *= inv[r];
  }

  // ---- G4: projF^T[e][token] += Wp^T[e][cc-half] @ out^T ; no barrier ----
  f32x4 accF[12];
#pragma unroll
  for (int m = 0; m < 12; ++m) accF[m] = fzero();
  {
    bf16x8 bfr[3];
    const int srcBase = l16 + ((lq & 1) << 5);
    const bool hiSel = (lq >= 2);
#pragma unroll
    for (int kt2 = 0; kt2 < 3; ++kt2) {
#pragma unroll
      for (int j = 0; j < 8; ++j) {
        int srcLane = srcBase + ((j >> 2) << 4);
        float va = __shfl(acc3[2*kt2][j & 3], srcLane);
        float vb = __shfl(acc3[2*kt2 + 1][j & 3], srcLane);
        bfr[kt2][j] = f2bfs(hiSel ? vb : va);
      }
    }
    const bf16x8* wpb = (const bf16x8*)wp_sw;
#pragma unroll
    for (int ms2 = 0; ms2 < 12; ++ms2) {
#pragma unroll
      for (int kt2 = 0; kt2 < 3; ++kt2) {
        bf16x8 wa = wpb[((3*h + kt2)*12 + ms2)*64 + lane];
        accF[ms2] = __builtin_amdgcn_mfma_f32_16x16x32_bf16(wa, bfr[kt2], accF[ms2], 0, 0, 0);
      }
    }
  }

  // ---- epilogue: combine halves in sEpi[token][e], add bias, store ----
  if (h == 0) {
#pragma unroll
    for (int ms2 = 0; ms2 < 12; ++ms2) {
      int e0 = ms2*16 + lq*4;
      f32x4 b4 = *(const f32x4*)(sBias + e0);
      f32x4 v = accF[ms2];
#pragma unroll
      for (int r = 0; r < 4; ++r) v[r] += b4[r];
      *(f32x4*)(sEpi + (q*16 + l16)*200 + e0) = v;
    }
  }
  __syncthreads();   // bar5
  if (h == 1) {
#pragma unroll
    for (int ms2 = 0; ms2 < 12; ++ms2) {
      int e0 = ms2*16 + lq*4;
      float* p = sEpi + (q*16 + l16)*200 + e0;
      f32x4 v = *(f32x4*)p;
#pragma unroll
      for (int r = 0; r < 4; ++r) v[r] += accF[ms2][r];
      *(f32x4*)p = v;
    }
  }
  __syncthreads();   // bar6

  {
    float* op = out + (size_t)blockIdx.x * 12288;
#pragma unroll
    for (int i = 0; i < 6; ++i) {
      int s = tid + i*512;            // 0..3071 float4 groups
      int token = s / 48;
      int e4 = s - token*48;
      f32x4 v = *(const f32x4*)(sEpi + token*200 + e4*4);
      *(f32x4*)(op + s*4) = v;
    }
  }
}

extern "C" void kernel_launch(void* const* d_in, const int* in_sizes, int n_in,
                              void* d_out, int out_size, void* d_ws, size_t ws_size,
                              hipStream_t stream) {
  const float* x     = (const float*)d_in[0];
  const float* wqkv  = (const float*)d_in[1];
  const float* wproj = (const float*)d_in[2];
  const float* bproj = (const float*)d_in[3];
  unsigned short* ws = (unsigned short*)d_ws;

  int nwin = in_sizes[0] / 12288;      // 4608 windows

  prepack_weights<<<72, 256, 0, stream>>>(wqkv, wproj, ws);
  win_attn_fused<<<nwin, 512, 0, stream>>>(x, ws, ws + WQKV_ELEMS, bproj, (float*)d_out);
}